// Round 4
// baseline (831.402 us; speedup 1.0000x reference)
//
#include <hip/hip_runtime.h>
#include <hip/hip_bf16.h>

// GCN forward: conv1(GEMM + sym-norm agg) -> BN -> PReLU -> conv2(GEMM + agg)
// N=100000, E=1600000, DIN=128, 2H=128, H=64. fp32 in/out.
//
// R4 changes vs R3 (425 us):
//  - agg1/agg2 XCD feature-slicing. R3's agg1: 210 MB L2-miss traffic at
//    ~3.9 TB/s (LLC random-read bound) because h (25.6 MB) >> per-XCD L2
//    (4 MB). Now h is stored in 8 column-slices of 16 features (3.2 MB per
//    slice); block's slice = blockIdx%8 which matches the round-robin
//    block->XCD dispatch, so each XCD's L2 holds its whole slice and the
//    random gather becomes L2-resident. Edge list re-read 8x (nontemporal).
//    Wave = 8 edge-groups x 8 uint-lanes, shuffle-xor reduce over groups.
//    Output chunks are full 64B lines per node -> no cross-XCD line sharing.
//  - agg2 same with 4 slices of 16 features (two XCDs per slice).
//  - GEMMs unchanged numerically; only their stores write sliced layouts.

#define DIN 128
#define F1  128   // 2H
#define F2  64    // H
#define BN_EPS 1e-5f
#define NODE_BSHIFT 8          // 256 nodes per bucket
#define NODE_BMASK  255
#define CHUNK 8192             // edges per binpass block
#define NPW 16                 // nodes per wave in sliced agg

__device__ __forceinline__ unsigned short f2bf(float f) {
    unsigned int u = __float_as_uint(f);
    u = u + 0x7fffu + ((u >> 16) & 1u);   // RNE
    return (unsigned short)(u >> 16);
}
__device__ __forceinline__ float bf_lo(unsigned int v) { return __uint_as_float(v << 16); }
__device__ __forceinline__ float bf_hi(unsigned int v) { return __uint_as_float(v & 0xffff0000u); }

// ---------------- graph build (unchanged from R3) ----------------

__global__ __launch_bounds__(256) void hist_k(const int* __restrict__ dst,
                                              int* __restrict__ bucketcnt,
                                              int e, int nbuck) {
    __shared__ int lh[512];
    int t = threadIdx.x;
    for (int i = t; i < 512; i += 256) lh[i] = 0;
    __syncthreads();
    int base = blockIdx.x * CHUNK;
    int end = base + CHUNK; if (end > e) end = e;
    for (int i = base + t; i < end; i += 256)
        atomicAdd(&lh[dst[i] >> NODE_BSHIFT], 1);
    __syncthreads();
    for (int b = t; b < nbuck; b += 256) {
        int v = lh[b];
        if (v) atomicAdd(&bucketcnt[b], v);
    }
}

__global__ __launch_bounds__(512) void bscan_k(const int* __restrict__ bucketcnt,
                                               int* __restrict__ bucketbase,
                                               int* __restrict__ bucketcur,
                                               int* __restrict__ rowptr,
                                               int nbuck, int n, int e) {
    __shared__ int s[512];
    int t = threadIdx.x;
    int orig = (t < nbuck) ? bucketcnt[t] : 0;
    s[t] = orig;
    __syncthreads();
    int run = orig;
    for (int ofs = 1; ofs < 512; ofs <<= 1) {
        int y = (t >= ofs) ? s[t - ofs] : 0;
        __syncthreads();
        run += y;
        s[t] = run;
        __syncthreads();
    }
    if (t < nbuck) {
        int excl = run - orig;
        bucketbase[t] = excl;
        bucketcur[t] = excl;
    }
    if (t == 0) {
        bucketbase[nbuck] = e;
        rowptr[n] = e;
    }
}

__global__ __launch_bounds__(256) void binpass_k(const int* __restrict__ src,
                                                 const int* __restrict__ dst,
                                                 int* __restrict__ bucketcur,
                                                 int2* __restrict__ pairs, int e) {
    __shared__ int lh[512], lbase[512], lrank[512];
    int t = threadIdx.x;
    for (int i = t; i < 512; i += 256) { lh[i] = 0; lrank[i] = 0; }
    __syncthreads();
    int base = blockIdx.x * CHUNK;
    int end = base + CHUNK; if (end > e) end = e;
    for (int i = base + t; i < end; i += 256)
        atomicAdd(&lh[dst[i] >> NODE_BSHIFT], 1);
    __syncthreads();
    for (int b = t; b < 512; b += 256) {
        int v = lh[b];
        lbase[b] = v ? atomicAdd(&bucketcur[b], v) : 0;
    }
    __syncthreads();
    for (int i = base + t; i < end; i += 256) {
        int sv = src[i], dv = dst[i];
        int b = dv >> NODE_BSHIFT;
        int r = atomicAdd(&lrank[b], 1);
        pairs[lbase[b] + r] = make_int2(sv, dv);
    }
}

__global__ __launch_bounds__(256) void bucket_k(const int2* __restrict__ pairs,
                                                const int* __restrict__ bucketbase,
                                                float* __restrict__ dinv,
                                                int* __restrict__ rowptr,
                                                int* __restrict__ srcsorted, int n) {
    __shared__ int lh[256], loff[256], lrank[256];
    int b = blockIdx.x, t = threadIdx.x;
    int e0 = bucketbase[b], e1 = bucketbase[b + 1];
    lh[t] = 0;
    lrank[t] = 0;
    __syncthreads();
    for (int i = e0 + t; i < e1; i += 256)
        atomicAdd(&lh[pairs[i].y & NODE_BMASK], 1);
    __syncthreads();
    int deg = lh[t];
    int run = deg;
    for (int ofs = 1; ofs < 256; ofs <<= 1) {
        int y = (t >= ofs) ? lh[t - ofs] : 0;
        __syncthreads();
        run += y;
        lh[t] = run;
        __syncthreads();
    }
    loff[t] = run - deg;
    int node = (b << NODE_BSHIFT) + t;
    if (node < n) {
        dinv[node] = rsqrtf((float)(deg + 1));   // +1 self-loop
        rowptr[node] = e0 + (run - deg);
    }
    __syncthreads();
    for (int i = e0 + t; i < e1; i += 256) {
        int2 p = pairs[i];
        int lo = p.y & NODE_BMASK;
        int r = atomicAdd(&lrank[lo], 1);
        srcsorted[e0 + loff[lo] + r] = p.x;
    }
}

// -------- GEMM1: ht(bf16, 8-sliced) = x @ W1  (N x 128 @ 128 x 128) --------
// ht layout: ht[slice][node][8 uints]  (slice = 16 features = 8 bf16x2)

__global__ __launch_bounds__(256) void gemm1_k(const float* __restrict__ x,
                                               const float* __restrict__ W,
                                               unsigned int* __restrict__ ht, int n) {
    __shared__ float xs[64][DIN];
    int t = threadIdx.x;
    int row0 = blockIdx.x * 64;
    const float4* x4 = (const float4*)x;
#pragma unroll
    for (int i = 0; i < 8; i++) {
        int l = t + i * 256;
        int r = l >> 5;
        int c = l & 31;
        float4 v = make_float4(0.f, 0.f, 0.f, 0.f);
        if (row0 + r < n) v = x4[(size_t)(row0 + r) * 32 + c];
        *(float4*)&xs[r][c * 4] = v;
    }
    __syncthreads();
    int cg = t & 31;
    int r0 = (t >> 5) * 8;
    float acc[8][4];
#pragma unroll
    for (int r = 0; r < 8; r++)
#pragma unroll
        for (int c = 0; c < 4; c++) acc[r][c] = 0.f;
    const float4* W4 = (const float4*)W;
#pragma unroll 4
    for (int k = 0; k < DIN; k++) {
        float4 bv = W4[k * 32 + cg];
#pragma unroll
        for (int r = 0; r < 8; r++) {
            float a = xs[r0 + r][k];
            acc[r][0] = fmaf(a, bv.x, acc[r][0]);
            acc[r][1] = fmaf(a, bv.y, acc[r][1]);
            acc[r][2] = fmaf(a, bv.z, acc[r][2]);
            acc[r][3] = fmaf(a, bv.w, acc[r][3]);
        }
    }
    int slice = cg >> 2;          // uints 2cg,2cg+1 -> slice (2cg)>>3
    int u = (cg * 2) & 7;
#pragma unroll
    for (int r = 0; r < 8; r++) {
        int row = row0 + r0 + r;
        if (row < n) {
            unsigned int p0 = (unsigned int)f2bf(acc[r][0]) | ((unsigned int)f2bf(acc[r][1]) << 16);
            unsigned int p1 = (unsigned int)f2bf(acc[r][2]) | ((unsigned int)f2bf(acc[r][3]) << 16);
            *(uint2*)&ht[(size_t)slice * n * 8 + (size_t)row * 8 + u] = make_uint2(p0, p1);
        }
    }
}

// ---- aggregation 1 (8-sliced): z = D^-1/2 (A+I) D^-1/2 h + b1 ----

__global__ __launch_bounds__(256) void agg1_k(const unsigned int* __restrict__ ht,
                                              const float* __restrict__ dinv,
                                              const int* __restrict__ rowptr,
                                              const int* __restrict__ srcs,
                                              const float* __restrict__ b1,
                                              float2* __restrict__ z, int n) {
    int slice = blockIdx.x & 7;        // matches round-robin block->XCD
    int grp = blockIdx.x >> 3;
    int wave = threadIdx.x >> 6;
    int lane = threadIdx.x & 63;
    int u = lane & 7;                  // uint (bf16 pair) within slice
    int eg = lane >> 3;                // edge group 0..7
    const unsigned int* hs = ht + (size_t)slice * n * 8;
    float2 bb = ((const float2*)b1)[slice * 8 + u];
    int nd0 = (grp * 4 + wave) * NPW;
    for (int i = 0; i < NPW; i++) {
        int nd = nd0 + i;
        if (nd >= n) return;
        int e0 = rowptr[nd], e1 = rowptr[nd + 1];
        float ax = 0.f, ay = 0.f;
        for (int e = e0 + eg; e < e1; e += 8) {
            int s = __builtin_nontemporal_load(&srcs[e]);
            float ds = dinv[s];
            unsigned int v = hs[(size_t)s * 8 + u];
            ax = fmaf(ds, bf_lo(v), ax);
            ay = fmaf(ds, bf_hi(v), ay);
        }
#pragma unroll
        for (int m = 8; m < 64; m <<= 1) {
            ax += __shfl_xor(ax, m, 64);
            ay += __shfl_xor(ay, m, 64);
        }
        if (eg == 0) {
            float di = dinv[nd];
            unsigned int sv = hs[(size_t)nd * 8 + u];
            ax = fmaf(di, bf_lo(sv), ax);
            ay = fmaf(di, bf_hi(sv), ay);
            float2 o;
            o.x = fmaf(ax, di, bb.x);
            o.y = fmaf(ay, di, bb.y);
            z[(size_t)nd * 64 + slice * 8 + u] = o;
        }
    }
}

// ---------------- BatchNorm stats ----------------

__global__ __launch_bounds__(128) void bnstats_k(const float* __restrict__ z,
                                                 double* __restrict__ bnacc, int n) {
    int f = threadIdx.x;
    float s = 0.f, q = 0.f;
    for (int r = blockIdx.x; r < n; r += gridDim.x) {
        float v = z[(size_t)r * F1 + f];
        s += v;
        q = fmaf(v, v, q);
    }
    atomicAdd(&bnacc[f], (double)s);
    atomicAdd(&bnacc[F1 + f], (double)q);
}

__global__ __launch_bounds__(128) void bnfinal_k(const double* __restrict__ bnacc,
                                                 const float* __restrict__ gamma,
                                                 const float* __restrict__ beta,
                                                 float* __restrict__ scale,
                                                 float* __restrict__ shift, int n) {
    int f = threadIdx.x;
    double mean = bnacc[f] / n;
    double var = bnacc[F1 + f] / n - mean * mean;
    float sc = gamma[f] * rsqrtf((float)var + BN_EPS);
    scale[f] = sc;
    shift[f] = beta[f] - (float)mean * sc;
}

// -- GEMM2: h2t(bf16, 4-sliced) = prelu(bn(z)) @ W2  (N x 128 @ 128 x 64) --

__global__ __launch_bounds__(256) void gemm2_k(const float* __restrict__ z,
                                               const float* __restrict__ W,
                                               const float* __restrict__ scale,
                                               const float* __restrict__ shift,
                                               const float* __restrict__ prelu_a,
                                               unsigned int* __restrict__ h2t, int n) {
    __shared__ float zs[64][F1];
    int t = threadIdx.x;
    int row0 = blockIdx.x * 64;
    float pa = prelu_a[0];
    const float4* z4 = (const float4*)z;
    const float4* sc4 = (const float4*)scale;
    const float4* sh4 = (const float4*)shift;
#pragma unroll
    for (int i = 0; i < 8; i++) {
        int l = t + i * 256;
        int r = l >> 5;
        int c = l & 31;
        float4 v = make_float4(0.f, 0.f, 0.f, 0.f);
        if (row0 + r < n) v = z4[(size_t)(row0 + r) * 32 + c];
        float4 sc = sc4[c], sh = sh4[c];
        v.x = fmaf(v.x, sc.x, sh.x); v.x = v.x >= 0.f ? v.x : pa * v.x;
        v.y = fmaf(v.y, sc.y, sh.y); v.y = v.y >= 0.f ? v.y : pa * v.y;
        v.z = fmaf(v.z, sc.z, sh.z); v.z = v.z >= 0.f ? v.z : pa * v.z;
        v.w = fmaf(v.w, sc.w, sh.w); v.w = v.w >= 0.f ? v.w : pa * v.w;
        *(float4*)&zs[r][c * 4] = v;
    }
    __syncthreads();
    int cg = t & 15;
    int r0 = (t >> 4) * 4;
    float acc[4][4];
#pragma unroll
    for (int r = 0; r < 4; r++)
#pragma unroll
        for (int c = 0; c < 4; c++) acc[r][c] = 0.f;
    const float4* W4 = (const float4*)W;
#pragma unroll 4
    for (int k = 0; k < F1; k++) {
        float4 bv = W4[k * 16 + cg];
#pragma unroll
        for (int r = 0; r < 4; r++) {
            float a = zs[r0 + r][k];
            acc[r][0] = fmaf(a, bv.x, acc[r][0]);
            acc[r][1] = fmaf(a, bv.y, acc[r][1]);
            acc[r][2] = fmaf(a, bv.z, acc[r][2]);
            acc[r][3] = fmaf(a, bv.w, acc[r][3]);
        }
    }
    int slice = cg >> 2;   // 0..3
    int u = (cg * 2) & 7;
#pragma unroll
    for (int r = 0; r < 4; r++) {
        int row = row0 + r0 + r;
        if (row < n) {
            unsigned int p0 = (unsigned int)f2bf(acc[r][0]) | ((unsigned int)f2bf(acc[r][1]) << 16);
            unsigned int p1 = (unsigned int)f2bf(acc[r][2]) | ((unsigned int)f2bf(acc[r][3]) << 16);
            *(uint2*)&h2t[(size_t)slice * n * 8 + (size_t)row * 8 + u] = make_uint2(p0, p1);
        }
    }
}

// ---- aggregation 2 (4-sliced, 2 XCDs per slice) -> output fp32 ----

__global__ __launch_bounds__(256) void agg2_k(const unsigned int* __restrict__ h2t,
                                              const float* __restrict__ dinv,
                                              const int* __restrict__ rowptr,
                                              const int* __restrict__ srcs,
                                              const float* __restrict__ b2,
                                              float2* __restrict__ out, int n) {
    int virt = blockIdx.x & 7;
    int slice = virt & 3;
    int half = virt >> 2;
    int grp = blockIdx.x >> 3;
    int wave = threadIdx.x >> 6;
    int lane = threadIdx.x & 63;
    int u = lane & 7;
    int eg = lane >> 3;
    const unsigned int* hs = h2t + (size_t)slice * n * 8;
    float2 bb = ((const float2*)b2)[slice * 8 + u];
    int nd0 = ((grp * 2 + half) * 4 + wave) * NPW;
    for (int i = 0; i < NPW; i++) {
        int nd = nd0 + i;
        if (nd >= n) return;
        int e0 = rowptr[nd], e1 = rowptr[nd + 1];
        float ax = 0.f, ay = 0.f;
        for (int e = e0 + eg; e < e1; e += 8) {
            int s = __builtin_nontemporal_load(&srcs[e]);
            float ds = dinv[s];
            unsigned int v = hs[(size_t)s * 8 + u];
            ax = fmaf(ds, bf_lo(v), ax);
            ay = fmaf(ds, bf_hi(v), ay);
        }
#pragma unroll
        for (int m = 8; m < 64; m <<= 1) {
            ax += __shfl_xor(ax, m, 64);
            ay += __shfl_xor(ay, m, 64);
        }
        if (eg == 0) {
            float di = dinv[nd];
            unsigned int sv = hs[(size_t)nd * 8 + u];
            ax = fmaf(di, bf_lo(sv), ax);
            ay = fmaf(di, bf_hi(sv), ay);
            float2 o;
            o.x = fmaf(ax, di, bb.x);
            o.y = fmaf(ay, di, bb.y);
            out[(size_t)nd * 32 + slice * 8 + u] = o;
        }
    }
}

// ---------------- launch ----------------

extern "C" void kernel_launch(void* const* d_in, const int* in_sizes, int n_in,
                              void* d_out, int out_size, void* d_ws, size_t ws_size,
                              hipStream_t stream) {
    const float* x       = (const float*)d_in[0];
    const int*   ei      = (const int*)d_in[1];
    const float* W1      = (const float*)d_in[2];
    const float* b1      = (const float*)d_in[3];
    const float* W2      = (const float*)d_in[4];
    const float* b2      = (const float*)d_in[5];
    const float* gamma   = (const float*)d_in[6];
    const float* beta    = (const float*)d_in[7];
    const float* prelu_a = (const float*)d_in[8];

    const int N = in_sizes[0] / DIN;
    const int E = in_sizes[1] / 2;
    const int* src = ei;
    const int* dst = ei + E;
    const int NBUCK = (N + NODE_BMASK) >> NODE_BSHIFT;  // 391

    char* p = (char*)d_ws;
    size_t off = 0;
    auto take = [&](size_t bytes) -> char* {
        char* r = p + off;
        off = (off + bytes + 255) & ~(size_t)255;
        return r;
    };
    int*          bucketcnt  = (int*)take(512 * 4);
    int*          bucketbase = (int*)take(513 * 4);
    int*          bucketcur  = (int*)take(512 * 4);
    float*        dinv       = (float*)take((size_t)N * 4);
    int*          rowptr     = (int*)take((size_t)(N + 1) * 4);
    int*          srcsorted  = (int*)take((size_t)E * 4);
    int2*         pairs      = (int2*)take((size_t)E * 8);
    double*       bnacc      = (double*)take(2 * F1 * 8);
    float*        scale      = (float*)take(F1 * 4);
    float*        shift      = (float*)take(F1 * 4);
    unsigned int* ht         = (unsigned int*)take((size_t)N * 64 * 4);  // 8-sliced bf16 h
    float*        z          = (float*)take((size_t)N * F1 * 4);
    unsigned int* h2t        = ht;  // ht dead after agg1; 4-sliced bf16 h2 (N*32 uints)
    float*        out        = (float*)d_out;

    hipMemsetAsync(bucketcnt, 0, 512 * 4, stream);
    hipMemsetAsync(bnacc, 0, 2 * F1 * 8, stream);

    const int eb = (E + CHUNK - 1) / CHUNK;

    hist_k<<<eb, 256, 0, stream>>>(dst, bucketcnt, E, NBUCK);
    bscan_k<<<1, 512, 0, stream>>>(bucketcnt, bucketbase, bucketcur, rowptr, NBUCK, N, E);
    binpass_k<<<eb, 256, 0, stream>>>(src, dst, bucketcur, pairs, E);
    bucket_k<<<NBUCK, 256, 0, stream>>>(pairs, bucketbase, dinv, rowptr, srcsorted, N);

    gemm1_k<<<(N + 63) / 64, 256, 0, stream>>>(x, W1, ht, N);

    const int G1 = (N + 4 * NPW - 1) / (4 * NPW);       // 64 nodes per block
    agg1_k<<<8 * G1, 256, 0, stream>>>(ht, dinv, rowptr, srcsorted, b1, (float2*)z, N);

    bnstats_k<<<512, F1, 0, stream>>>(z, bnacc, N);
    bnfinal_k<<<1, F1, 0, stream>>>(bnacc, gamma, beta, scale, shift, N);

    gemm2_k<<<(N + 63) / 64, 256, 0, stream>>>(z, W2, scale, shift, prelu_a, h2t, N);

    const int G2 = (N + 8 * NPW - 1) / (8 * NPW);       // 128 nodes per 2 blocks
    agg2_k<<<8 * G2, 256, 0, stream>>>(h2t, dinv, rowptr, srcsorted, b2, (float2*)out, N);
}

// Round 5
// 694.323 us; speedup vs baseline: 1.1974x; 1.1974x over previous
//
#include <hip/hip_runtime.h>
#include <hip/hip_bf16.h>

// GCN forward: conv1(GEMM + sym-norm agg) -> BN -> PReLU -> conv2(GEMM + agg)
// N=100000, E=1600000, DIN=128, 2H=128, H=64. fp32 in/out.
//
// R5 changes vs R4 (831 us):
//  - Keep XCD feature-slicing (R4 proved it: FETCH 210->133 MB) but drop the
//    shuffle-reduce wave layout that caused the 5x regression (352 us agg1 at
//    0.53 TB/s = latency-bound on 6-deep shfl chains, not bandwidth).
//  - New agg layout: lane = sub*8+u; each 8-lane group owns ONE node's
//    16-feature slice and walks its edge list 4-way unrolled (R3-style MLP,
//    zero shuffles). Instruction count per edge matches R3; gathers now hit
//    the XCD-local L2. Stores remain one full 64B line per (node,slice).

#define DIN 128
#define F1  128   // 2H
#define F2  64    // H
#define BN_EPS 1e-5f
#define NODE_BSHIFT 8          // 256 nodes per bucket
#define NODE_BMASK  255
#define CHUNK 8192             // edges per binpass block
#define K1 4                   // node-iters per wave (8 nodes each), agg1
#define K2 4                   // node-iters per wave, agg2

__device__ __forceinline__ unsigned short f2bf(float f) {
    unsigned int u = __float_as_uint(f);
    u = u + 0x7fffu + ((u >> 16) & 1u);   // RNE
    return (unsigned short)(u >> 16);
}
__device__ __forceinline__ float bf_lo(unsigned int v) { return __uint_as_float(v << 16); }
__device__ __forceinline__ float bf_hi(unsigned int v) { return __uint_as_float(v & 0xffff0000u); }

// ---------------- graph build (unchanged from R3) ----------------

__global__ __launch_bounds__(256) void hist_k(const int* __restrict__ dst,
                                              int* __restrict__ bucketcnt,
                                              int e, int nbuck) {
    __shared__ int lh[512];
    int t = threadIdx.x;
    for (int i = t; i < 512; i += 256) lh[i] = 0;
    __syncthreads();
    int base = blockIdx.x * CHUNK;
    int end = base + CHUNK; if (end > e) end = e;
    for (int i = base + t; i < end; i += 256)
        atomicAdd(&lh[dst[i] >> NODE_BSHIFT], 1);
    __syncthreads();
    for (int b = t; b < nbuck; b += 256) {
        int v = lh[b];
        if (v) atomicAdd(&bucketcnt[b], v);
    }
}

__global__ __launch_bounds__(512) void bscan_k(const int* __restrict__ bucketcnt,
                                               int* __restrict__ bucketbase,
                                               int* __restrict__ bucketcur,
                                               int* __restrict__ rowptr,
                                               int nbuck, int n, int e) {
    __shared__ int s[512];
    int t = threadIdx.x;
    int orig = (t < nbuck) ? bucketcnt[t] : 0;
    s[t] = orig;
    __syncthreads();
    int run = orig;
    for (int ofs = 1; ofs < 512; ofs <<= 1) {
        int y = (t >= ofs) ? s[t - ofs] : 0;
        __syncthreads();
        run += y;
        s[t] = run;
        __syncthreads();
    }
    if (t < nbuck) {
        int excl = run - orig;
        bucketbase[t] = excl;
        bucketcur[t] = excl;
    }
    if (t == 0) {
        bucketbase[nbuck] = e;
        rowptr[n] = e;
    }
}

__global__ __launch_bounds__(256) void binpass_k(const int* __restrict__ src,
                                                 const int* __restrict__ dst,
                                                 int* __restrict__ bucketcur,
                                                 int2* __restrict__ pairs, int e) {
    __shared__ int lh[512], lbase[512], lrank[512];
    int t = threadIdx.x;
    for (int i = t; i < 512; i += 256) { lh[i] = 0; lrank[i] = 0; }
    __syncthreads();
    int base = blockIdx.x * CHUNK;
    int end = base + CHUNK; if (end > e) end = e;
    for (int i = base + t; i < end; i += 256)
        atomicAdd(&lh[dst[i] >> NODE_BSHIFT], 1);
    __syncthreads();
    for (int b = t; b < 512; b += 256) {
        int v = lh[b];
        lbase[b] = v ? atomicAdd(&bucketcur[b], v) : 0;
    }
    __syncthreads();
    for (int i = base + t; i < end; i += 256) {
        int sv = src[i], dv = dst[i];
        int b = dv >> NODE_BSHIFT;
        int r = atomicAdd(&lrank[b], 1);
        pairs[lbase[b] + r] = make_int2(sv, dv);
    }
}

__global__ __launch_bounds__(256) void bucket_k(const int2* __restrict__ pairs,
                                                const int* __restrict__ bucketbase,
                                                float* __restrict__ dinv,
                                                int* __restrict__ rowptr,
                                                int* __restrict__ srcsorted, int n) {
    __shared__ int lh[256], loff[256], lrank[256];
    int b = blockIdx.x, t = threadIdx.x;
    int e0 = bucketbase[b], e1 = bucketbase[b + 1];
    lh[t] = 0;
    lrank[t] = 0;
    __syncthreads();
    for (int i = e0 + t; i < e1; i += 256)
        atomicAdd(&lh[pairs[i].y & NODE_BMASK], 1);
    __syncthreads();
    int deg = lh[t];
    int run = deg;
    for (int ofs = 1; ofs < 256; ofs <<= 1) {
        int y = (t >= ofs) ? lh[t - ofs] : 0;
        __syncthreads();
        run += y;
        lh[t] = run;
        __syncthreads();
    }
    loff[t] = run - deg;
    int node = (b << NODE_BSHIFT) + t;
    if (node < n) {
        dinv[node] = rsqrtf((float)(deg + 1));   // +1 self-loop
        rowptr[node] = e0 + (run - deg);
    }
    __syncthreads();
    for (int i = e0 + t; i < e1; i += 256) {
        int2 p = pairs[i];
        int lo = p.y & NODE_BMASK;
        int r = atomicAdd(&lrank[lo], 1);
        srcsorted[e0 + loff[lo] + r] = p.x;
    }
}

// -------- GEMM1: ht(bf16, 8-sliced) = x @ W1  (N x 128 @ 128 x 128) --------
// ht layout: ht[slice][node][8 uints]  (slice = 16 features = 8 bf16x2)

__global__ __launch_bounds__(256) void gemm1_k(const float* __restrict__ x,
                                               const float* __restrict__ W,
                                               unsigned int* __restrict__ ht, int n) {
    __shared__ float xs[64][DIN];
    int t = threadIdx.x;
    int row0 = blockIdx.x * 64;
    const float4* x4 = (const float4*)x;
#pragma unroll
    for (int i = 0; i < 8; i++) {
        int l = t + i * 256;
        int r = l >> 5;
        int c = l & 31;
        float4 v = make_float4(0.f, 0.f, 0.f, 0.f);
        if (row0 + r < n) v = x4[(size_t)(row0 + r) * 32 + c];
        *(float4*)&xs[r][c * 4] = v;
    }
    __syncthreads();
    int cg = t & 31;
    int r0 = (t >> 5) * 8;
    float acc[8][4];
#pragma unroll
    for (int r = 0; r < 8; r++)
#pragma unroll
        for (int c = 0; c < 4; c++) acc[r][c] = 0.f;
    const float4* W4 = (const float4*)W;
#pragma unroll 4
    for (int k = 0; k < DIN; k++) {
        float4 bv = W4[k * 32 + cg];
#pragma unroll
        for (int r = 0; r < 8; r++) {
            float a = xs[r0 + r][k];
            acc[r][0] = fmaf(a, bv.x, acc[r][0]);
            acc[r][1] = fmaf(a, bv.y, acc[r][1]);
            acc[r][2] = fmaf(a, bv.z, acc[r][2]);
            acc[r][3] = fmaf(a, bv.w, acc[r][3]);
        }
    }
    int slice = cg >> 2;
    int u = (cg * 2) & 7;
#pragma unroll
    for (int r = 0; r < 8; r++) {
        int row = row0 + r0 + r;
        if (row < n) {
            unsigned int p0 = (unsigned int)f2bf(acc[r][0]) | ((unsigned int)f2bf(acc[r][1]) << 16);
            unsigned int p1 = (unsigned int)f2bf(acc[r][2]) | ((unsigned int)f2bf(acc[r][3]) << 16);
            *(uint2*)&ht[(size_t)slice * n * 8 + (size_t)row * 8 + u] = make_uint2(p0, p1);
        }
    }
}

// ---- aggregation 1 (8-sliced, reduction-free): z = D^-1/2 (A+I) D^-1/2 h + b1 ----
// wave: 8 node-groups x 8 feature-lanes; each group walks one node's edges.

__global__ __launch_bounds__(256) void agg1_k(const unsigned int* __restrict__ ht,
                                              const float* __restrict__ dinv,
                                              const int* __restrict__ rowptr,
                                              const int* __restrict__ srcs,
                                              const float* __restrict__ b1,
                                              float2* __restrict__ z, int n) {
    int slice = blockIdx.x & 7;        // matches round-robin block->XCD
    int grp = blockIdx.x >> 3;
    int wave = threadIdx.x >> 6;
    int lane = threadIdx.x & 63;
    int sub = lane >> 3;               // node sub-index 0..7
    int u = lane & 7;                  // uint (bf16 pair) within slice
    const unsigned int* hs = ht + (size_t)slice * n * 8;
    float2 bb = ((const float2*)b1)[slice * 8 + u];
    int nd0 = (grp * 4 + wave) * (8 * K1) + sub;
#pragma unroll
    for (int i = 0; i < K1; i++) {
        int nd = nd0 + i * 8;
        if (nd < n) {
            int e = rowptr[nd], e1 = rowptr[nd + 1];
            float ax = 0.f, ay = 0.f;
            for (; e + 4 <= e1; e += 4) {
                int s0 = __builtin_nontemporal_load(&srcs[e]);
                int s1 = __builtin_nontemporal_load(&srcs[e + 1]);
                int s2 = __builtin_nontemporal_load(&srcs[e + 2]);
                int s3 = __builtin_nontemporal_load(&srcs[e + 3]);
                float d0 = dinv[s0], d1 = dinv[s1], d2 = dinv[s2], d3 = dinv[s3];
                unsigned int v0 = hs[(size_t)s0 * 8 + u];
                unsigned int v1 = hs[(size_t)s1 * 8 + u];
                unsigned int v2 = hs[(size_t)s2 * 8 + u];
                unsigned int v3 = hs[(size_t)s3 * 8 + u];
                ax = fmaf(d0, bf_lo(v0), ax); ay = fmaf(d0, bf_hi(v0), ay);
                ax = fmaf(d1, bf_lo(v1), ax); ay = fmaf(d1, bf_hi(v1), ay);
                ax = fmaf(d2, bf_lo(v2), ax); ay = fmaf(d2, bf_hi(v2), ay);
                ax = fmaf(d3, bf_lo(v3), ax); ay = fmaf(d3, bf_hi(v3), ay);
            }
            for (; e < e1; e++) {
                int s = __builtin_nontemporal_load(&srcs[e]);
                float ds = dinv[s];
                unsigned int v = hs[(size_t)s * 8 + u];
                ax = fmaf(ds, bf_lo(v), ax);
                ay = fmaf(ds, bf_hi(v), ay);
            }
            float di = dinv[nd];
            unsigned int sv = hs[(size_t)nd * 8 + u];
            ax = fmaf(di, bf_lo(sv), ax);
            ay = fmaf(di, bf_hi(sv), ay);
            float2 o;
            o.x = fmaf(ax, di, bb.x);
            o.y = fmaf(ay, di, bb.y);
            z[(size_t)nd * 64 + slice * 8 + u] = o;   // 8 lanes -> one 64B line
        }
    }
}

// ---------------- BatchNorm stats ----------------

__global__ __launch_bounds__(128) void bnstats_k(const float* __restrict__ z,
                                                 double* __restrict__ bnacc, int n) {
    int f = threadIdx.x;
    float s = 0.f, q = 0.f;
    for (int r = blockIdx.x; r < n; r += gridDim.x) {
        float v = z[(size_t)r * F1 + f];
        s += v;
        q = fmaf(v, v, q);
    }
    atomicAdd(&bnacc[f], (double)s);
    atomicAdd(&bnacc[F1 + f], (double)q);
}

__global__ __launch_bounds__(128) void bnfinal_k(const double* __restrict__ bnacc,
                                                 const float* __restrict__ gamma,
                                                 const float* __restrict__ beta,
                                                 float* __restrict__ scale,
                                                 float* __restrict__ shift, int n) {
    int f = threadIdx.x;
    double mean = bnacc[f] / n;
    double var = bnacc[F1 + f] / n - mean * mean;
    float sc = gamma[f] * rsqrtf((float)var + BN_EPS);
    scale[f] = sc;
    shift[f] = beta[f] - (float)mean * sc;
}

// -- GEMM2: h2t(bf16, 4-sliced) = prelu(bn(z)) @ W2  (N x 128 @ 128 x 64) --

__global__ __launch_bounds__(256) void gemm2_k(const float* __restrict__ z,
                                               const float* __restrict__ W,
                                               const float* __restrict__ scale,
                                               const float* __restrict__ shift,
                                               const float* __restrict__ prelu_a,
                                               unsigned int* __restrict__ h2t, int n) {
    __shared__ float zs[64][F1];
    int t = threadIdx.x;
    int row0 = blockIdx.x * 64;
    float pa = prelu_a[0];
    const float4* z4 = (const float4*)z;
    const float4* sc4 = (const float4*)scale;
    const float4* sh4 = (const float4*)shift;
#pragma unroll
    for (int i = 0; i < 8; i++) {
        int l = t + i * 256;
        int r = l >> 5;
        int c = l & 31;
        float4 v = make_float4(0.f, 0.f, 0.f, 0.f);
        if (row0 + r < n) v = z4[(size_t)(row0 + r) * 32 + c];
        float4 sc = sc4[c], sh = sh4[c];
        v.x = fmaf(v.x, sc.x, sh.x); v.x = v.x >= 0.f ? v.x : pa * v.x;
        v.y = fmaf(v.y, sc.y, sh.y); v.y = v.y >= 0.f ? v.y : pa * v.y;
        v.z = fmaf(v.z, sc.z, sh.z); v.z = v.z >= 0.f ? v.z : pa * v.z;
        v.w = fmaf(v.w, sc.w, sh.w); v.w = v.w >= 0.f ? v.w : pa * v.w;
        *(float4*)&zs[r][c * 4] = v;
    }
    __syncthreads();
    int cg = t & 15;
    int r0 = (t >> 4) * 4;
    float acc[4][4];
#pragma unroll
    for (int r = 0; r < 4; r++)
#pragma unroll
        for (int c = 0; c < 4; c++) acc[r][c] = 0.f;
    const float4* W4 = (const float4*)W;
#pragma unroll 4
    for (int k = 0; k < F1; k++) {
        float4 bv = W4[k * 16 + cg];
#pragma unroll
        for (int r = 0; r < 4; r++) {
            float a = zs[r0 + r][k];
            acc[r][0] = fmaf(a, bv.x, acc[r][0]);
            acc[r][1] = fmaf(a, bv.y, acc[r][1]);
            acc[r][2] = fmaf(a, bv.z, acc[r][2]);
            acc[r][3] = fmaf(a, bv.w, acc[r][3]);
        }
    }
    int slice = cg >> 2;   // 0..3
    int u = (cg * 2) & 7;
#pragma unroll
    for (int r = 0; r < 4; r++) {
        int row = row0 + r0 + r;
        if (row < n) {
            unsigned int p0 = (unsigned int)f2bf(acc[r][0]) | ((unsigned int)f2bf(acc[r][1]) << 16);
            unsigned int p1 = (unsigned int)f2bf(acc[r][2]) | ((unsigned int)f2bf(acc[r][3]) << 16);
            *(uint2*)&h2t[(size_t)slice * n * 8 + (size_t)row * 8 + u] = make_uint2(p0, p1);
        }
    }
}

// ---- aggregation 2 (4-sliced x 2 halves, reduction-free) -> output fp32 ----

__global__ __launch_bounds__(256) void agg2_k(const unsigned int* __restrict__ h2t,
                                              const float* __restrict__ dinv,
                                              const int* __restrict__ rowptr,
                                              const int* __restrict__ srcs,
                                              const float* __restrict__ b2,
                                              float2* __restrict__ out, int n) {
    int virt = blockIdx.x & 7;
    int slice = virt & 3;
    int half = virt >> 2;
    int grp = blockIdx.x >> 3;
    int wave = threadIdx.x >> 6;
    int lane = threadIdx.x & 63;
    int sub = lane >> 3;
    int u = lane & 7;
    const unsigned int* hs = h2t + (size_t)slice * n * 8;
    float2 bb = ((const float2*)b2)[slice * 8 + u];
    int nd0 = ((grp * 2 + half) * 4 + wave) * (8 * K2) + sub;
#pragma unroll
    for (int i = 0; i < K2; i++) {
        int nd = nd0 + i * 8;
        if (nd < n) {
            int e = rowptr[nd], e1 = rowptr[nd + 1];
            float ax = 0.f, ay = 0.f;
            for (; e + 4 <= e1; e += 4) {
                int s0 = __builtin_nontemporal_load(&srcs[e]);
                int s1 = __builtin_nontemporal_load(&srcs[e + 1]);
                int s2 = __builtin_nontemporal_load(&srcs[e + 2]);
                int s3 = __builtin_nontemporal_load(&srcs[e + 3]);
                float d0 = dinv[s0], d1 = dinv[s1], d2 = dinv[s2], d3 = dinv[s3];
                unsigned int v0 = hs[(size_t)s0 * 8 + u];
                unsigned int v1 = hs[(size_t)s1 * 8 + u];
                unsigned int v2 = hs[(size_t)s2 * 8 + u];
                unsigned int v3 = hs[(size_t)s3 * 8 + u];
                ax = fmaf(d0, bf_lo(v0), ax); ay = fmaf(d0, bf_hi(v0), ay);
                ax = fmaf(d1, bf_lo(v1), ax); ay = fmaf(d1, bf_hi(v1), ay);
                ax = fmaf(d2, bf_lo(v2), ax); ay = fmaf(d2, bf_hi(v2), ay);
                ax = fmaf(d3, bf_lo(v3), ax); ay = fmaf(d3, bf_hi(v3), ay);
            }
            for (; e < e1; e++) {
                int s = __builtin_nontemporal_load(&srcs[e]);
                float ds = dinv[s];
                unsigned int v = hs[(size_t)s * 8 + u];
                ax = fmaf(ds, bf_lo(v), ax);
                ay = fmaf(ds, bf_hi(v), ay);
            }
            float di = dinv[nd];
            unsigned int sv = hs[(size_t)nd * 8 + u];
            ax = fmaf(di, bf_lo(sv), ax);
            ay = fmaf(di, bf_hi(sv), ay);
            float2 o;
            o.x = fmaf(ax, di, bb.x);
            o.y = fmaf(ay, di, bb.y);
            out[(size_t)nd * 32 + slice * 8 + u] = o;  // 8 lanes -> one 64B line
        }
    }
}

// ---------------- launch ----------------

extern "C" void kernel_launch(void* const* d_in, const int* in_sizes, int n_in,
                              void* d_out, int out_size, void* d_ws, size_t ws_size,
                              hipStream_t stream) {
    const float* x       = (const float*)d_in[0];
    const int*   ei      = (const int*)d_in[1];
    const float* W1      = (const float*)d_in[2];
    const float* b1      = (const float*)d_in[3];
    const float* W2      = (const float*)d_in[4];
    const float* b2      = (const float*)d_in[5];
    const float* gamma   = (const float*)d_in[6];
    const float* beta    = (const float*)d_in[7];
    const float* prelu_a = (const float*)d_in[8];

    const int N = in_sizes[0] / DIN;
    const int E = in_sizes[1] / 2;
    const int* src = ei;
    const int* dst = ei + E;
    const int NBUCK = (N + NODE_BMASK) >> NODE_BSHIFT;  // 391

    char* p = (char*)d_ws;
    size_t off = 0;
    auto take = [&](size_t bytes) -> char* {
        char* r = p + off;
        off = (off + bytes + 255) & ~(size_t)255;
        return r;
    };
    int*          bucketcnt  = (int*)take(512 * 4);
    int*          bucketbase = (int*)take(513 * 4);
    int*          bucketcur  = (int*)take(512 * 4);
    float*        dinv       = (float*)take((size_t)N * 4);
    int*          rowptr     = (int*)take((size_t)(N + 1) * 4);
    int*          srcsorted  = (int*)take((size_t)E * 4);
    int2*         pairs      = (int2*)take((size_t)E * 8);
    double*       bnacc      = (double*)take(2 * F1 * 8);
    float*        scale      = (float*)take(F1 * 4);
    float*        shift      = (float*)take(F1 * 4);
    unsigned int* ht         = (unsigned int*)take((size_t)N * 64 * 4);  // 8-sliced bf16 h
    float*        z          = (float*)take((size_t)N * F1 * 4);
    unsigned int* h2t        = ht;  // ht dead after agg1; 4-sliced bf16 h2 (N*32 uints)
    float*        out        = (float*)d_out;

    hipMemsetAsync(bucketcnt, 0, 512 * 4, stream);
    hipMemsetAsync(bnacc, 0, 2 * F1 * 8, stream);

    const int eb = (E + CHUNK - 1) / CHUNK;

    hist_k<<<eb, 256, 0, stream>>>(dst, bucketcnt, E, NBUCK);
    bscan_k<<<1, 512, 0, stream>>>(bucketcnt, bucketbase, bucketcur, rowptr, NBUCK, N, E);
    binpass_k<<<eb, 256, 0, stream>>>(src, dst, bucketcur, pairs, E);
    bucket_k<<<NBUCK, 256, 0, stream>>>(pairs, bucketbase, dinv, rowptr, srcsorted, N);

    gemm1_k<<<(N + 63) / 64, 256, 0, stream>>>(x, W1, ht, N);

    const int NPB1 = 4 * 8 * K1;                        // 128 nodes per block
    const int G1 = (N + NPB1 - 1) / NPB1;
    agg1_k<<<8 * G1, 256, 0, stream>>>(ht, dinv, rowptr, srcsorted, b1, (float2*)z, N);

    bnstats_k<<<512, F1, 0, stream>>>(z, bnacc, N);
    bnfinal_k<<<1, F1, 0, stream>>>(bnacc, gamma, beta, scale, shift, N);

    gemm2_k<<<(N + 63) / 64, 256, 0, stream>>>(z, W2, scale, shift, prelu_a, h2t, N);

    const int NPB2 = 2 * 4 * 8 * K2;                    // 256 nodes per 2 blocks
    const int G2 = (N + NPB2 - 1) / NPB2;
    agg2_k<<<8 * G2, 256, 0, stream>>>(h2t, dinv, rowptr, srcsorted, b2, (float2*)out, N);
}

// Round 6
// 467.934 us; speedup vs baseline: 1.7768x; 1.4838x over previous
//
#include <hip/hip_runtime.h>
#include <hip/hip_bf16.h>

// GCN forward: conv1(GEMM + sym-norm agg) -> BN -> PReLU -> conv2(GEMM + agg)
// N=100000, E=1600000, DIN=128, 2H=128, H=64. fp32 in/out.
//
// R6 changes vs R5 (694 us):
//  - XCD slicing ABANDONED (R5 FETCH=214MB = 8x25.6MB = zero slice residency;
//    blockIdx%8->XCD does not hold). Revert to R3's wave-per-node full-row
//    coalesced gather (best measured: 68 us agg1 at 3.9 TB/s).
//  - h rows pre-scaled by dinv[src] in GEMM epilogues (h' = dinv*h, bf16):
//    agg inner loop is src->gather->add, no random dinv loads, shorter dep
//    chain, 8-deep unroll for MLP.
//  - z stored bf16: halves agg1 write, bnstats read, gemm2 staging read.
//  - agg1: 4 nodes/block (4 waves x 64 lanes); agg2: 8 nodes/block (8
//    half-waves x 32 lanes, row=128B).

#define DIN 128
#define F1  128   // 2H
#define F2  64    // H
#define BN_EPS 1e-5f
#define NODE_BSHIFT 8          // 256 nodes per bucket
#define NODE_BMASK  255
#define CHUNK 8192             // edges per binpass block

__device__ __forceinline__ unsigned short f2bf(float f) {
    unsigned int u = __float_as_uint(f);
    u = u + 0x7fffu + ((u >> 16) & 1u);   // RNE
    return (unsigned short)(u >> 16);
}
__device__ __forceinline__ float bf_lo(unsigned int v) { return __uint_as_float(v << 16); }
__device__ __forceinline__ float bf_hi(unsigned int v) { return __uint_as_float(v & 0xffff0000u); }

// ---------------- graph build (unchanged from R3) ----------------

__global__ __launch_bounds__(256) void hist_k(const int* __restrict__ dst,
                                              int* __restrict__ bucketcnt,
                                              int e, int nbuck) {
    __shared__ int lh[512];
    int t = threadIdx.x;
    for (int i = t; i < 512; i += 256) lh[i] = 0;
    __syncthreads();
    int base = blockIdx.x * CHUNK;
    int end = base + CHUNK; if (end > e) end = e;
    for (int i = base + t; i < end; i += 256)
        atomicAdd(&lh[dst[i] >> NODE_BSHIFT], 1);
    __syncthreads();
    for (int b = t; b < nbuck; b += 256) {
        int v = lh[b];
        if (v) atomicAdd(&bucketcnt[b], v);
    }
}

__global__ __launch_bounds__(512) void bscan_k(const int* __restrict__ bucketcnt,
                                               int* __restrict__ bucketbase,
                                               int* __restrict__ bucketcur,
                                               int* __restrict__ rowptr,
                                               int nbuck, int n, int e) {
    __shared__ int s[512];
    int t = threadIdx.x;
    int orig = (t < nbuck) ? bucketcnt[t] : 0;
    s[t] = orig;
    __syncthreads();
    int run = orig;
    for (int ofs = 1; ofs < 512; ofs <<= 1) {
        int y = (t >= ofs) ? s[t - ofs] : 0;
        __syncthreads();
        run += y;
        s[t] = run;
        __syncthreads();
    }
    if (t < nbuck) {
        int excl = run - orig;
        bucketbase[t] = excl;
        bucketcur[t] = excl;
    }
    if (t == 0) {
        bucketbase[nbuck] = e;
        rowptr[n] = e;
    }
}

__global__ __launch_bounds__(256) void binpass_k(const int* __restrict__ src,
                                                 const int* __restrict__ dst,
                                                 int* __restrict__ bucketcur,
                                                 int2* __restrict__ pairs, int e) {
    __shared__ int lh[512], lbase[512], lrank[512];
    int t = threadIdx.x;
    for (int i = t; i < 512; i += 256) { lh[i] = 0; lrank[i] = 0; }
    __syncthreads();
    int base = blockIdx.x * CHUNK;
    int end = base + CHUNK; if (end > e) end = e;
    for (int i = base + t; i < end; i += 256)
        atomicAdd(&lh[dst[i] >> NODE_BSHIFT], 1);
    __syncthreads();
    for (int b = t; b < 512; b += 256) {
        int v = lh[b];
        lbase[b] = v ? atomicAdd(&bucketcur[b], v) : 0;
    }
    __syncthreads();
    for (int i = base + t; i < end; i += 256) {
        int sv = src[i], dv = dst[i];
        int b = dv >> NODE_BSHIFT;
        int r = atomicAdd(&lrank[b], 1);
        pairs[lbase[b] + r] = make_int2(sv, dv);
    }
}

__global__ __launch_bounds__(256) void bucket_k(const int2* __restrict__ pairs,
                                                const int* __restrict__ bucketbase,
                                                float* __restrict__ dinv,
                                                int* __restrict__ rowptr,
                                                int* __restrict__ srcsorted, int n) {
    __shared__ int lh[256], loff[256], lrank[256];
    int b = blockIdx.x, t = threadIdx.x;
    int e0 = bucketbase[b], e1 = bucketbase[b + 1];
    lh[t] = 0;
    lrank[t] = 0;
    __syncthreads();
    for (int i = e0 + t; i < e1; i += 256)
        atomicAdd(&lh[pairs[i].y & NODE_BMASK], 1);
    __syncthreads();
    int deg = lh[t];
    int run = deg;
    for (int ofs = 1; ofs < 256; ofs <<= 1) {
        int y = (t >= ofs) ? lh[t - ofs] : 0;
        __syncthreads();
        run += y;
        lh[t] = run;
        __syncthreads();
    }
    loff[t] = run - deg;
    int node = (b << NODE_BSHIFT) + t;
    if (node < n) {
        dinv[node] = rsqrtf((float)(deg + 1));   // +1 self-loop
        rowptr[node] = e0 + (run - deg);
    }
    __syncthreads();
    for (int i = e0 + t; i < e1; i += 256) {
        int2 p = pairs[i];
        int lo = p.y & NODE_BMASK;
        int r = atomicAdd(&lrank[lo], 1);
        srcsorted[e0 + loff[lo] + r] = p.x;
    }
}

// -------- GEMM1: h'(bf16) = dinv[row] * (x @ W1)  (N x 128 @ 128 x 128) --------

__global__ __launch_bounds__(256) void gemm1_k(const float* __restrict__ x,
                                               const float* __restrict__ W,
                                               const float* __restrict__ dinv,
                                               unsigned int* __restrict__ h, int n) {
    __shared__ float xs[64][DIN];
    int t = threadIdx.x;
    int row0 = blockIdx.x * 64;
    const float4* x4 = (const float4*)x;
#pragma unroll
    for (int i = 0; i < 8; i++) {
        int l = t + i * 256;
        int r = l >> 5;
        int c = l & 31;
        float4 v = make_float4(0.f, 0.f, 0.f, 0.f);
        if (row0 + r < n) v = x4[(size_t)(row0 + r) * 32 + c];
        *(float4*)&xs[r][c * 4] = v;
    }
    __syncthreads();
    int cg = t & 31;
    int r0 = (t >> 5) * 8;
    float acc[8][4];
#pragma unroll
    for (int r = 0; r < 8; r++)
#pragma unroll
        for (int c = 0; c < 4; c++) acc[r][c] = 0.f;
    const float4* W4 = (const float4*)W;
#pragma unroll 4
    for (int k = 0; k < DIN; k++) {
        float4 bv = W4[k * 32 + cg];
#pragma unroll
        for (int r = 0; r < 8; r++) {
            float a = xs[r0 + r][k];
            acc[r][0] = fmaf(a, bv.x, acc[r][0]);
            acc[r][1] = fmaf(a, bv.y, acc[r][1]);
            acc[r][2] = fmaf(a, bv.z, acc[r][2]);
            acc[r][3] = fmaf(a, bv.w, acc[r][3]);
        }
    }
    uint2* h2v = (uint2*)h;
#pragma unroll
    for (int r = 0; r < 8; r++) {
        int row = row0 + r0 + r;
        if (row < n) {
            float di = dinv[row];
            unsigned int p0 = (unsigned int)f2bf(di * acc[r][0]) | ((unsigned int)f2bf(di * acc[r][1]) << 16);
            unsigned int p1 = (unsigned int)f2bf(di * acc[r][2]) | ((unsigned int)f2bf(di * acc[r][3]) << 16);
            h2v[(size_t)row * 32 + cg] = make_uint2(p0, p1);
        }
    }
}

// ---- agg1: z(bf16) = di*(sum_{s} h'[s] + h'[nd]) + b1 ; wave-per-node ----

__global__ __launch_bounds__(256) void agg1_k(const unsigned int* __restrict__ h,
                                              const float* __restrict__ dinv,
                                              const int* __restrict__ rowptr,
                                              const int* __restrict__ srcs,
                                              const float* __restrict__ b1,
                                              unsigned int* __restrict__ z, int n) {
    int wave = threadIdx.x >> 6;
    int f = threadIdx.x & 63;          // uint (bf16 pair) index in row
    int nd = blockIdx.x * 4 + wave;
    if (nd >= n) return;
    int e = rowptr[nd], e1 = rowptr[nd + 1];
    float ax = 0.f, ay = 0.f;
    for (; e + 8 <= e1; e += 8) {
        int s0 = __builtin_nontemporal_load(&srcs[e]);
        int s1 = __builtin_nontemporal_load(&srcs[e + 1]);
        int s2 = __builtin_nontemporal_load(&srcs[e + 2]);
        int s3 = __builtin_nontemporal_load(&srcs[e + 3]);
        int s4 = __builtin_nontemporal_load(&srcs[e + 4]);
        int s5 = __builtin_nontemporal_load(&srcs[e + 5]);
        int s6 = __builtin_nontemporal_load(&srcs[e + 6]);
        int s7 = __builtin_nontemporal_load(&srcs[e + 7]);
        unsigned int v0 = h[(size_t)s0 * 64 + f];
        unsigned int v1 = h[(size_t)s1 * 64 + f];
        unsigned int v2 = h[(size_t)s2 * 64 + f];
        unsigned int v3 = h[(size_t)s3 * 64 + f];
        unsigned int v4 = h[(size_t)s4 * 64 + f];
        unsigned int v5 = h[(size_t)s5 * 64 + f];
        unsigned int v6 = h[(size_t)s6 * 64 + f];
        unsigned int v7 = h[(size_t)s7 * 64 + f];
        ax += bf_lo(v0); ay += bf_hi(v0);
        ax += bf_lo(v1); ay += bf_hi(v1);
        ax += bf_lo(v2); ay += bf_hi(v2);
        ax += bf_lo(v3); ay += bf_hi(v3);
        ax += bf_lo(v4); ay += bf_hi(v4);
        ax += bf_lo(v5); ay += bf_hi(v5);
        ax += bf_lo(v6); ay += bf_hi(v6);
        ax += bf_lo(v7); ay += bf_hi(v7);
    }
    for (; e < e1; e++) {
        int s = __builtin_nontemporal_load(&srcs[e]);
        unsigned int v = h[(size_t)s * 64 + f];
        ax += bf_lo(v);
        ay += bf_hi(v);
    }
    unsigned int sv = h[(size_t)nd * 64 + f];   // self: h'[nd] = di*h[nd]
    ax += bf_lo(sv);
    ay += bf_hi(sv);
    float di = dinv[nd];
    float2 bb = ((const float2*)b1)[f];
    float zx = fmaf(ax, di, bb.x);
    float zy = fmaf(ay, di, bb.y);
    z[(size_t)nd * 64 + f] = (unsigned int)f2bf(zx) | ((unsigned int)f2bf(zy) << 16);
}

// ---------------- BatchNorm stats (bf16 z) ----------------

__global__ __launch_bounds__(64) void bnstats_k(const unsigned int* __restrict__ z,
                                                double* __restrict__ bnacc, int n) {
    int f = threadIdx.x;   // uint idx -> feats 2f, 2f+1
    float sx = 0.f, qx = 0.f, sy = 0.f, qy = 0.f;
    for (int r = blockIdx.x; r < n; r += gridDim.x) {
        unsigned int v = z[(size_t)r * 64 + f];
        float a = bf_lo(v), b = bf_hi(v);
        sx += a; qx = fmaf(a, a, qx);
        sy += b; qy = fmaf(b, b, qy);
    }
    atomicAdd(&bnacc[2 * f], (double)sx);
    atomicAdd(&bnacc[F1 + 2 * f], (double)qx);
    atomicAdd(&bnacc[2 * f + 1], (double)sy);
    atomicAdd(&bnacc[F1 + 2 * f + 1], (double)qy);
}

__global__ __launch_bounds__(128) void bnfinal_k(const double* __restrict__ bnacc,
                                                 const float* __restrict__ gamma,
                                                 const float* __restrict__ beta,
                                                 float* __restrict__ scale,
                                                 float* __restrict__ shift, int n) {
    int f = threadIdx.x;
    double mean = bnacc[f] / n;
    double var = bnacc[F1 + f] / n - mean * mean;
    float sc = gamma[f] * rsqrtf((float)var + BN_EPS);
    scale[f] = sc;
    shift[f] = beta[f] - (float)mean * sc;
}

// -- GEMM2: h2'(bf16) = dinv[row] * (prelu(bn(z)) @ W2)  (N x 128 @ 128 x 64) --

__global__ __launch_bounds__(256) void gemm2_k(const unsigned int* __restrict__ z,
                                               const float* __restrict__ W,
                                               const float* __restrict__ scale,
                                               const float* __restrict__ shift,
                                               const float* __restrict__ prelu_a,
                                               const float* __restrict__ dinv,
                                               unsigned int* __restrict__ h2, int n) {
    __shared__ float zs[64][F1];
    int t = threadIdx.x;
    int row0 = blockIdx.x * 64;
    float pa = prelu_a[0];
    const float2* sc2 = (const float2*)scale;
    const float2* sh2 = (const float2*)shift;
#pragma unroll
    for (int i = 0; i < 16; i++) {
        int l = t + i * 256;       // uint idx in 64x64-uint tile (4096)
        int r = l >> 6;
        int c = l & 63;
        unsigned int v = 0;
        if (row0 + r < n) v = z[(size_t)(row0 + r) * 64 + c];
        float2 sc = sc2[c], sh = sh2[c];
        float a = fmaf(bf_lo(v), sc.x, sh.x); a = a >= 0.f ? a : pa * a;
        float b = fmaf(bf_hi(v), sc.y, sh.y); b = b >= 0.f ? b : pa * b;
        zs[r][2 * c] = a;
        zs[r][2 * c + 1] = b;
    }
    __syncthreads();
    int cg = t & 15;
    int r0 = (t >> 4) * 4;
    float acc[4][4];
#pragma unroll
    for (int r = 0; r < 4; r++)
#pragma unroll
        for (int c = 0; c < 4; c++) acc[r][c] = 0.f;
    const float4* W4 = (const float4*)W;
#pragma unroll 4
    for (int k = 0; k < F1; k++) {
        float4 bv = W4[k * 16 + cg];
#pragma unroll
        for (int r = 0; r < 4; r++) {
            float a = zs[r0 + r][k];
            acc[r][0] = fmaf(a, bv.x, acc[r][0]);
            acc[r][1] = fmaf(a, bv.y, acc[r][1]);
            acc[r][2] = fmaf(a, bv.z, acc[r][2]);
            acc[r][3] = fmaf(a, bv.w, acc[r][3]);
        }
    }
    uint2* o2 = (uint2*)h2;
#pragma unroll
    for (int r = 0; r < 4; r++) {
        int row = row0 + r0 + r;
        if (row < n) {
            float di = dinv[row];
            unsigned int p0 = (unsigned int)f2bf(di * acc[r][0]) | ((unsigned int)f2bf(di * acc[r][1]) << 16);
            unsigned int p1 = (unsigned int)f2bf(di * acc[r][2]) | ((unsigned int)f2bf(di * acc[r][3]) << 16);
            o2[(size_t)row * 16 + cg] = make_uint2(p0, p1);
        }
    }
}

// ---- agg2: out(fp32) = di*(sum h2'[s] + h2'[nd]) + b2 ; half-wave per node ----

__global__ __launch_bounds__(256) void agg2_k(const unsigned int* __restrict__ h2,
                                              const float* __restrict__ dinv,
                                              const int* __restrict__ rowptr,
                                              const int* __restrict__ srcs,
                                              const float* __restrict__ b2,
                                              float2* __restrict__ out, int n) {
    int half = threadIdx.x >> 5;       // 0..7
    int f = threadIdx.x & 31;          // uint idx in 32-uint row
    int nd = blockIdx.x * 8 + half;
    if (nd >= n) return;
    int e = rowptr[nd], e1 = rowptr[nd + 1];
    float ax = 0.f, ay = 0.f;
    for (; e + 8 <= e1; e += 8) {
        int s0 = __builtin_nontemporal_load(&srcs[e]);
        int s1 = __builtin_nontemporal_load(&srcs[e + 1]);
        int s2 = __builtin_nontemporal_load(&srcs[e + 2]);
        int s3 = __builtin_nontemporal_load(&srcs[e + 3]);
        int s4 = __builtin_nontemporal_load(&srcs[e + 4]);
        int s5 = __builtin_nontemporal_load(&srcs[e + 5]);
        int s6 = __builtin_nontemporal_load(&srcs[e + 6]);
        int s7 = __builtin_nontemporal_load(&srcs[e + 7]);
        unsigned int v0 = h2[(size_t)s0 * 32 + f];
        unsigned int v1 = h2[(size_t)s1 * 32 + f];
        unsigned int v2 = h2[(size_t)s2 * 32 + f];
        unsigned int v3 = h2[(size_t)s3 * 32 + f];
        unsigned int v4 = h2[(size_t)s4 * 32 + f];
        unsigned int v5 = h2[(size_t)s5 * 32 + f];
        unsigned int v6 = h2[(size_t)s6 * 32 + f];
        unsigned int v7 = h2[(size_t)s7 * 32 + f];
        ax += bf_lo(v0); ay += bf_hi(v0);
        ax += bf_lo(v1); ay += bf_hi(v1);
        ax += bf_lo(v2); ay += bf_hi(v2);
        ax += bf_lo(v3); ay += bf_hi(v3);
        ax += bf_lo(v4); ay += bf_hi(v4);
        ax += bf_lo(v5); ay += bf_hi(v5);
        ax += bf_lo(v6); ay += bf_hi(v6);
        ax += bf_lo(v7); ay += bf_hi(v7);
    }
    for (; e < e1; e++) {
        int s = __builtin_nontemporal_load(&srcs[e]);
        unsigned int v = h2[(size_t)s * 32 + f];
        ax += bf_lo(v);
        ay += bf_hi(v);
    }
    unsigned int sv = h2[(size_t)nd * 32 + f];
    ax += bf_lo(sv);
    ay += bf_hi(sv);
    float di = dinv[nd];
    float2 bb = ((const float2*)b2)[f];
    float2 o;
    o.x = fmaf(ax, di, bb.x);
    o.y = fmaf(ay, di, bb.y);
    out[(size_t)nd * 32 + f] = o;
}

// ---------------- launch ----------------

extern "C" void kernel_launch(void* const* d_in, const int* in_sizes, int n_in,
                              void* d_out, int out_size, void* d_ws, size_t ws_size,
                              hipStream_t stream) {
    const float* x       = (const float*)d_in[0];
    const int*   ei      = (const int*)d_in[1];
    const float* W1      = (const float*)d_in[2];
    const float* b1      = (const float*)d_in[3];
    const float* W2      = (const float*)d_in[4];
    const float* b2      = (const float*)d_in[5];
    const float* gamma   = (const float*)d_in[6];
    const float* beta    = (const float*)d_in[7];
    const float* prelu_a = (const float*)d_in[8];

    const int N = in_sizes[0] / DIN;
    const int E = in_sizes[1] / 2;
    const int* src = ei;
    const int* dst = ei + E;
    const int NBUCK = (N + NODE_BMASK) >> NODE_BSHIFT;  // 391

    char* p = (char*)d_ws;
    size_t off = 0;
    auto take = [&](size_t bytes) -> char* {
        char* r = p + off;
        off = (off + bytes + 255) & ~(size_t)255;
        return r;
    };
    int*          bucketcnt  = (int*)take(512 * 4);
    int*          bucketbase = (int*)take(513 * 4);
    int*          bucketcur  = (int*)take(512 * 4);
    float*        dinv       = (float*)take((size_t)N * 4);
    int*          rowptr     = (int*)take((size_t)(N + 1) * 4);
    int*          srcsorted  = (int*)take((size_t)E * 4);
    int2*         pairs      = (int2*)take((size_t)E * 8);
    double*       bnacc      = (double*)take(2 * F1 * 8);
    float*        scale      = (float*)take(F1 * 4);
    float*        shift      = (float*)take(F1 * 4);
    unsigned int* h          = (unsigned int*)take((size_t)N * 64 * 4);  // bf16 h' (128 feats)
    unsigned int* z          = (unsigned int*)take((size_t)N * 64 * 4);  // bf16 z (128 feats)
    unsigned int* h2         = h;  // h dead after agg1; bf16 h2' (64 feats, N*32 uints)
    float*        out        = (float*)d_out;

    hipMemsetAsync(bucketcnt, 0, 512 * 4, stream);
    hipMemsetAsync(bnacc, 0, 2 * F1 * 8, stream);

    const int eb = (E + CHUNK - 1) / CHUNK;

    hist_k<<<eb, 256, 0, stream>>>(dst, bucketcnt, E, NBUCK);
    bscan_k<<<1, 512, 0, stream>>>(bucketcnt, bucketbase, bucketcur, rowptr, NBUCK, N, E);
    binpass_k<<<eb, 256, 0, stream>>>(src, dst, bucketcur, pairs, E);
    bucket_k<<<NBUCK, 256, 0, stream>>>(pairs, bucketbase, dinv, rowptr, srcsorted, N);

    gemm1_k<<<(N + 63) / 64, 256, 0, stream>>>(x, W1, dinv, h, N);
    agg1_k<<<(N + 3) / 4, 256, 0, stream>>>(h, dinv, rowptr, srcsorted, b1, z, N);
    bnstats_k<<<512, 64, 0, stream>>>(z, bnacc, N);
    bnfinal_k<<<1, F1, 0, stream>>>(bnacc, gamma, beta, scale, shift, N);
    gemm2_k<<<(N + 63) / 64, 256, 0, stream>>>(z, W2, scale, shift, prelu_a, dinv, h2, N);
    agg2_k<<<(N + 7) / 8, 256, 0, stream>>>(h2, dinv, rowptr, srcsorted, b2, (float2*)out, N);
}

// Round 7
// 425.599 us; speedup vs baseline: 1.9535x; 1.0995x over previous
//
#include <hip/hip_runtime.h>
#include <hip/hip_bf16.h>

// GCN forward: conv1(GEMM + sym-norm agg) -> BN -> PReLU -> conv2(GEMM + agg)
// N=100000, E=1600000, DIN=128, 2H=128, H=64. fp32 in/out.
//
// R7 changes vs R6 (467 us):
//  - agg1 regression root-caused: 8-unroll left a ~3.5-iter serial scalar
//    tail per node (Poisson-16 degrees) -> waves stall in dependent-load
//    chains (BW 3.9->2.5 TB/s, VALUBusy up). Fix is structural:
//    PADDED CSR - every node's edge count padded to a multiple of 4; pad
//    slots reference dummy node N whose h row is zeroed. Agg loop is an
//    exact-trip 4-unrolled loop: no tail, no divergence. Pad slots hit the
//    cached zero row (~0 extra HBM bytes).
//  - agg1 back to R3's measured-best launch shape: one wave per node,
//    <<<N,64>>>, plain loads. agg2: two half-wave nodes per 64-thread block.
//  - build gains bdeg_k (padded per-bucket totals) + pscan_k (391-scan).

#define DIN 128
#define F1  128   // 2H
#define F2  64    // H
#define BN_EPS 1e-5f
#define NODE_BSHIFT 8          // 256 nodes per bucket
#define NODE_BMASK  255
#define CHUNK 8192             // edges per binpass block

__device__ __forceinline__ unsigned short f2bf(float f) {
    unsigned int u = __float_as_uint(f);
    u = u + 0x7fffu + ((u >> 16) & 1u);   // RNE
    return (unsigned short)(u >> 16);
}
__device__ __forceinline__ float bf_lo(unsigned int v) { return __uint_as_float(v << 16); }
__device__ __forceinline__ float bf_hi(unsigned int v) { return __uint_as_float(v & 0xffff0000u); }

// ---------------- graph build ----------------

__global__ __launch_bounds__(256) void hist_k(const int* __restrict__ dst,
                                              int* __restrict__ bucketcnt,
                                              int e, int nbuck) {
    __shared__ int lh[512];
    int t = threadIdx.x;
    for (int i = t; i < 512; i += 256) lh[i] = 0;
    __syncthreads();
    int base = blockIdx.x * CHUNK;
    int end = base + CHUNK; if (end > e) end = e;
    for (int i = base + t; i < end; i += 256)
        atomicAdd(&lh[dst[i] >> NODE_BSHIFT], 1);
    __syncthreads();
    for (int b = t; b < nbuck; b += 256) {
        int v = lh[b];
        if (v) atomicAdd(&bucketcnt[b], v);
    }
}

// exclusive scan of unpadded bucket counts -> pairs layout
__global__ __launch_bounds__(512) void bscan_k(const int* __restrict__ bucketcnt,
                                               int* __restrict__ bucketbase,
                                               int* __restrict__ bucketcur,
                                               int nbuck, int e) {
    __shared__ int s[512];
    int t = threadIdx.x;
    int orig = (t < nbuck) ? bucketcnt[t] : 0;
    s[t] = orig;
    __syncthreads();
    int run = orig;
    for (int ofs = 1; ofs < 512; ofs <<= 1) {
        int y = (t >= ofs) ? s[t - ofs] : 0;
        __syncthreads();
        run += y;
        s[t] = run;
        __syncthreads();
    }
    if (t < nbuck) {
        int excl = run - orig;
        bucketbase[t] = excl;
        bucketcur[t] = excl;
    }
    if (t == 0) bucketbase[nbuck] = e;
}

__global__ __launch_bounds__(256) void binpass_k(const int* __restrict__ src,
                                                 const int* __restrict__ dst,
                                                 int* __restrict__ bucketcur,
                                                 int2* __restrict__ pairs, int e) {
    __shared__ int lh[512], lbase[512], lrank[512];
    int t = threadIdx.x;
    for (int i = t; i < 512; i += 256) { lh[i] = 0; lrank[i] = 0; }
    __syncthreads();
    int base = blockIdx.x * CHUNK;
    int end = base + CHUNK; if (end > e) end = e;
    for (int i = base + t; i < end; i += 256)
        atomicAdd(&lh[dst[i] >> NODE_BSHIFT], 1);
    __syncthreads();
    for (int b = t; b < 512; b += 256) {
        int v = lh[b];
        lbase[b] = v ? atomicAdd(&bucketcur[b], v) : 0;
    }
    __syncthreads();
    for (int i = base + t; i < end; i += 256) {
        int sv = src[i], dv = dst[i];
        int b = dv >> NODE_BSHIFT;
        int r = atomicAdd(&lrank[b], 1);
        pairs[lbase[b] + r] = make_int2(sv, dv);
    }
}

// per-node degree + padded (mult-of-4) per-bucket totals
__global__ __launch_bounds__(256) void bdeg_k(const int2* __restrict__ pairs,
                                              const int* __restrict__ bucketbase,
                                              int* __restrict__ degi,
                                              int* __restrict__ pbucketcnt, int n) {
    __shared__ int lh[256], red[256];
    int b = blockIdx.x, t = threadIdx.x;
    int e0 = bucketbase[b], e1 = bucketbase[b + 1];
    lh[t] = 0;
    __syncthreads();
    for (int i = e0 + t; i < e1; i += 256)
        atomicAdd(&lh[pairs[i].y & NODE_BMASK], 1);
    __syncthreads();
    int node = (b << NODE_BSHIFT) + t;
    int deg = lh[t];
    int pdeg = (node < n) ? ((deg + 3) & ~3) : 0;
    if (node < n) degi[node] = deg;
    red[t] = pdeg;
    __syncthreads();
    for (int ofs = 128; ofs > 0; ofs >>= 1) {
        if (t < ofs) red[t] += red[t + ofs];
        __syncthreads();
    }
    if (t == 0) pbucketcnt[b] = red[0];
}

// exclusive scan of padded bucket totals -> srcsorted layout
__global__ __launch_bounds__(512) void pscan_k(const int* __restrict__ pbucketcnt,
                                               int* __restrict__ pbase,
                                               int* __restrict__ rowptr,
                                               int nbuck, int n) {
    __shared__ int s[512];
    int t = threadIdx.x;
    int orig = (t < nbuck) ? pbucketcnt[t] : 0;
    s[t] = orig;
    __syncthreads();
    int run = orig;
    for (int ofs = 1; ofs < 512; ofs <<= 1) {
        int y = (t >= ofs) ? s[t - ofs] : 0;
        __syncthreads();
        run += y;
        s[t] = run;
        __syncthreads();
    }
    if (t < nbuck) pbase[t] = run - orig;
    if (t == 0) {
        pbase[nbuck] = 0;  // unused
        // total padded edges
    }
    if (t == nbuck - 1) rowptr[n] = run;
}

// fine scatter into padded per-node regions; pad slots -> dummy node n
__global__ __launch_bounds__(256) void bucket2_k(const int2* __restrict__ pairs,
                                                 const int* __restrict__ bucketbase,
                                                 const int* __restrict__ degi,
                                                 const int* __restrict__ pbase,
                                                 float* __restrict__ dinv,
                                                 int* __restrict__ rowptr,
                                                 int* __restrict__ srcsorted, int n) {
    __shared__ int ps[256], loff[256], lrank[256];
    int b = blockIdx.x, t = threadIdx.x;
    int e0 = bucketbase[b], e1 = bucketbase[b + 1];
    int node = (b << NODE_BSHIFT) + t;
    int deg = (node < n) ? degi[node] : 0;
    int pdeg = (deg + 3) & ~3;
    lrank[t] = 0;
    ps[t] = pdeg;
    __syncthreads();
    int run = pdeg;
    for (int ofs = 1; ofs < 256; ofs <<= 1) {
        int y = (t >= ofs) ? ps[t - ofs] : 0;
        __syncthreads();
        run += y;
        ps[t] = run;
        __syncthreads();
    }
    int o = pbase[b] + (run - pdeg);
    loff[t] = o;
    if (node < n) {
        dinv[node] = rsqrtf((float)(deg + 1));   // +1 self-loop
        rowptr[node] = o;
    }
    __syncthreads();
    for (int i = e0 + t; i < e1; i += 256) {
        int2 p = pairs[i];
        int lo = p.y & NODE_BMASK;
        int r = atomicAdd(&lrank[lo], 1);
        srcsorted[loff[lo] + r] = p.x;
    }
    if (node < n)
        for (int i = deg; i < pdeg; i++) srcsorted[o + i] = n;   // pads -> zero row
}

// -------- GEMM1: h'(bf16) = dinv[row] * (x @ W1)  (N x 128 @ 128 x 128) --------

__global__ __launch_bounds__(256) void gemm1_k(const float* __restrict__ x,
                                               const float* __restrict__ W,
                                               const float* __restrict__ dinv,
                                               unsigned int* __restrict__ h, int n) {
    __shared__ float xs[64][DIN];
    int t = threadIdx.x;
    int row0 = blockIdx.x * 64;
    const float4* x4 = (const float4*)x;
#pragma unroll
    for (int i = 0; i < 8; i++) {
        int l = t + i * 256;
        int r = l >> 5;
        int c = l & 31;
        float4 v = make_float4(0.f, 0.f, 0.f, 0.f);
        if (row0 + r < n) v = x4[(size_t)(row0 + r) * 32 + c];
        *(float4*)&xs[r][c * 4] = v;
    }
    __syncthreads();
    int cg = t & 31;
    int r0 = (t >> 5) * 8;
    float acc[8][4];
#pragma unroll
    for (int r = 0; r < 8; r++)
#pragma unroll
        for (int c = 0; c < 4; c++) acc[r][c] = 0.f;
    const float4* W4 = (const float4*)W;
#pragma unroll 4
    for (int k = 0; k < DIN; k++) {
        float4 bv = W4[k * 32 + cg];
#pragma unroll
        for (int r = 0; r < 8; r++) {
            float a = xs[r0 + r][k];
            acc[r][0] = fmaf(a, bv.x, acc[r][0]);
            acc[r][1] = fmaf(a, bv.y, acc[r][1]);
            acc[r][2] = fmaf(a, bv.z, acc[r][2]);
            acc[r][3] = fmaf(a, bv.w, acc[r][3]);
        }
    }
    uint2* h2v = (uint2*)h;
#pragma unroll
    for (int r = 0; r < 8; r++) {
        int row = row0 + r0 + r;
        if (row < n) {
            float di = dinv[row];
            unsigned int p0 = (unsigned int)f2bf(di * acc[r][0]) | ((unsigned int)f2bf(di * acc[r][1]) << 16);
            unsigned int p1 = (unsigned int)f2bf(di * acc[r][2]) | ((unsigned int)f2bf(di * acc[r][3]) << 16);
            h2v[(size_t)row * 32 + cg] = make_uint2(p0, p1);
        }
    }
}

// ---- agg1: z(bf16) = di*(sum_s h'[s] + h'[nd]) + b1 ; one wave per node ----
// padded CSR: trip count exact multiple of 4, no tail.

__global__ __launch_bounds__(64) void agg1_k(const unsigned int* __restrict__ h,
                                             const float* __restrict__ dinv,
                                             const int* __restrict__ rowptr,
                                             const int* __restrict__ srcs,
                                             const float* __restrict__ b1,
                                             unsigned int* __restrict__ z, int n) {
    int nd = blockIdx.x;
    int f = threadIdx.x;               // uint (bf16 pair) index, 0..63
    int e = rowptr[nd], e1 = rowptr[nd + 1];
    float ax = 0.f, ay = 0.f;
    for (; e < e1; e += 4) {
        int s0 = srcs[e], s1 = srcs[e + 1], s2 = srcs[e + 2], s3 = srcs[e + 3];
        unsigned int v0 = h[(size_t)s0 * 64 + f];
        unsigned int v1 = h[(size_t)s1 * 64 + f];
        unsigned int v2 = h[(size_t)s2 * 64 + f];
        unsigned int v3 = h[(size_t)s3 * 64 + f];
        ax += bf_lo(v0); ay += bf_hi(v0);
        ax += bf_lo(v1); ay += bf_hi(v1);
        ax += bf_lo(v2); ay += bf_hi(v2);
        ax += bf_lo(v3); ay += bf_hi(v3);
    }
    unsigned int sv = h[(size_t)nd * 64 + f];   // self: h'[nd] = di*h[nd]
    ax += bf_lo(sv);
    ay += bf_hi(sv);
    float di = dinv[nd];
    float2 bb = ((const float2*)b1)[f];
    float zx = fmaf(ax, di, bb.x);
    float zy = fmaf(ay, di, bb.y);
    z[(size_t)nd * 64 + f] = (unsigned int)f2bf(zx) | ((unsigned int)f2bf(zy) << 16);
}

// ---------------- BatchNorm stats (bf16 z) ----------------

__global__ __launch_bounds__(64) void bnstats_k(const unsigned int* __restrict__ z,
                                                double* __restrict__ bnacc, int n) {
    int f = threadIdx.x;   // uint idx -> feats 2f, 2f+1
    float sx = 0.f, qx = 0.f, sy = 0.f, qy = 0.f;
    for (int r = blockIdx.x; r < n; r += gridDim.x) {
        unsigned int v = z[(size_t)r * 64 + f];
        float a = bf_lo(v), b = bf_hi(v);
        sx += a; qx = fmaf(a, a, qx);
        sy += b; qy = fmaf(b, b, qy);
    }
    atomicAdd(&bnacc[2 * f], (double)sx);
    atomicAdd(&bnacc[F1 + 2 * f], (double)qx);
    atomicAdd(&bnacc[2 * f + 1], (double)sy);
    atomicAdd(&bnacc[F1 + 2 * f + 1], (double)qy);
}

__global__ __launch_bounds__(128) void bnfinal_k(const double* __restrict__ bnacc,
                                                 const float* __restrict__ gamma,
                                                 const float* __restrict__ beta,
                                                 float* __restrict__ scale,
                                                 float* __restrict__ shift, int n) {
    int f = threadIdx.x;
    double mean = bnacc[f] / n;
    double var = bnacc[F1 + f] / n - mean * mean;
    float sc = gamma[f] * rsqrtf((float)var + BN_EPS);
    scale[f] = sc;
    shift[f] = beta[f] - (float)mean * sc;
}

// -- GEMM2: h2'(bf16) = dinv[row] * (prelu(bn(z)) @ W2)  (N x 128 @ 128 x 64) --

__global__ __launch_bounds__(256) void gemm2_k(const unsigned int* __restrict__ z,
                                               const float* __restrict__ W,
                                               const float* __restrict__ scale,
                                               const float* __restrict__ shift,
                                               const float* __restrict__ prelu_a,
                                               const float* __restrict__ dinv,
                                               unsigned int* __restrict__ h2, int n) {
    __shared__ float zs[64][F1];
    int t = threadIdx.x;
    int row0 = blockIdx.x * 64;
    float pa = prelu_a[0];
    const float2* sc2 = (const float2*)scale;
    const float2* sh2 = (const float2*)shift;
#pragma unroll
    for (int i = 0; i < 16; i++) {
        int l = t + i * 256;       // uint idx in 64x64-uint tile (4096)
        int r = l >> 6;
        int c = l & 63;
        unsigned int v = 0;
        if (row0 + r < n) v = z[(size_t)(row0 + r) * 64 + c];
        float2 sc = sc2[c], sh = sh2[c];
        float a = fmaf(bf_lo(v), sc.x, sh.x); a = a >= 0.f ? a : pa * a;
        float b = fmaf(bf_hi(v), sc.y, sh.y); b = b >= 0.f ? b : pa * b;
        zs[r][2 * c] = a;
        zs[r][2 * c + 1] = b;
    }
    __syncthreads();
    int cg = t & 15;
    int r0 = (t >> 4) * 4;
    float acc[4][4];
#pragma unroll
    for (int r = 0; r < 4; r++)
#pragma unroll
        for (int c = 0; c < 4; c++) acc[r][c] = 0.f;
    const float4* W4 = (const float4*)W;
#pragma unroll 4
    for (int k = 0; k < F1; k++) {
        float4 bv = W4[k * 16 + cg];
#pragma unroll
        for (int r = 0; r < 4; r++) {
            float a = zs[r0 + r][k];
            acc[r][0] = fmaf(a, bv.x, acc[r][0]);
            acc[r][1] = fmaf(a, bv.y, acc[r][1]);
            acc[r][2] = fmaf(a, bv.z, acc[r][2]);
            acc[r][3] = fmaf(a, bv.w, acc[r][3]);
        }
    }
    uint2* o2 = (uint2*)h2;
#pragma unroll
    for (int r = 0; r < 4; r++) {
        int row = row0 + r0 + r;
        if (row < n) {
            float di = dinv[row];
            unsigned int p0 = (unsigned int)f2bf(di * acc[r][0]) | ((unsigned int)f2bf(di * acc[r][1]) << 16);
            unsigned int p1 = (unsigned int)f2bf(di * acc[r][2]) | ((unsigned int)f2bf(di * acc[r][3]) << 16);
            o2[(size_t)row * 16 + cg] = make_uint2(p0, p1);
        }
    }
}

// ---- agg2: out(fp32) = di*(sum h2'[s] + h2'[nd]) + b2 ; 2 half-wave nodes/block ----

__global__ __launch_bounds__(64) void agg2_k(const unsigned int* __restrict__ h2,
                                             const float* __restrict__ dinv,
                                             const int* __restrict__ rowptr,
                                             const int* __restrict__ srcs,
                                             const float* __restrict__ b2,
                                             float2* __restrict__ out, int n) {
    int half = threadIdx.x >> 5;       // 0..1
    int f = threadIdx.x & 31;          // uint idx in 32-uint row
    int nd = blockIdx.x * 2 + half;
    if (nd >= n) return;
    int e = rowptr[nd], e1 = rowptr[nd + 1];
    float ax = 0.f, ay = 0.f;
    for (; e < e1; e += 4) {
        int s0 = srcs[e], s1 = srcs[e + 1], s2 = srcs[e + 2], s3 = srcs[e + 3];
        unsigned int v0 = h2[(size_t)s0 * 32 + f];
        unsigned int v1 = h2[(size_t)s1 * 32 + f];
        unsigned int v2 = h2[(size_t)s2 * 32 + f];
        unsigned int v3 = h2[(size_t)s3 * 32 + f];
        ax += bf_lo(v0); ay += bf_hi(v0);
        ax += bf_lo(v1); ay += bf_hi(v1);
        ax += bf_lo(v2); ay += bf_hi(v2);
        ax += bf_lo(v3); ay += bf_hi(v3);
    }
    unsigned int sv = h2[(size_t)nd * 32 + f];
    ax += bf_lo(sv);
    ay += bf_hi(sv);
    float di = dinv[nd];
    float2 bb = ((const float2*)b2)[f];
    float2 o;
    o.x = fmaf(ax, di, bb.x);
    o.y = fmaf(ay, di, bb.y);
    out[(size_t)nd * 32 + f] = o;
}

// ---------------- launch ----------------

extern "C" void kernel_launch(void* const* d_in, const int* in_sizes, int n_in,
                              void* d_out, int out_size, void* d_ws, size_t ws_size,
                              hipStream_t stream) {
    const float* x       = (const float*)d_in[0];
    const int*   ei      = (const int*)d_in[1];
    const float* W1      = (const float*)d_in[2];
    const float* b1      = (const float*)d_in[3];
    const float* W2      = (const float*)d_in[4];
    const float* b2      = (const float*)d_in[5];
    const float* gamma   = (const float*)d_in[6];
    const float* beta    = (const float*)d_in[7];
    const float* prelu_a = (const float*)d_in[8];

    const int N = in_sizes[0] / DIN;
    const int E = in_sizes[1] / 2;
    const int* src = ei;
    const int* dst = ei + E;
    const int NBUCK = (N + NODE_BMASK) >> NODE_BSHIFT;  // 391

    char* p = (char*)d_ws;
    size_t off = 0;
    auto take = [&](size_t bytes) -> char* {
        char* r = p + off;
        off = (off + bytes + 255) & ~(size_t)255;
        return r;
    };
    int*          bucketcnt  = (int*)take(512 * 4);
    int*          bucketbase = (int*)take(513 * 4);
    int*          bucketcur  = (int*)take(512 * 4);
    int*          pbucketcnt = (int*)take(512 * 4);
    int*          pbase      = (int*)take(513 * 4);
    int*          degi       = (int*)take((size_t)N * 4);
    float*        dinv       = (float*)take((size_t)N * 4);
    int*          rowptr     = (int*)take((size_t)(N + 1) * 4);
    int*          srcsorted  = (int*)take((size_t)(E + 4 * N) * 4);
    int2*         pairs      = (int2*)take((size_t)E * 8);
    double*       bnacc      = (double*)take(2 * F1 * 8);
    float*        scale      = (float*)take(F1 * 4);
    float*        shift      = (float*)take(F1 * 4);
    unsigned int* h          = (unsigned int*)take((size_t)(N + 1) * 64 * 4);  // bf16 h' + zero row
    unsigned int* z          = (unsigned int*)take((size_t)N * 64 * 4);        // bf16 z
    unsigned int* h2         = h;  // h dead after agg1; bf16 h2' ((N+1)*32 uints fits)
    float*        out        = (float*)d_out;

    hipMemsetAsync(bucketcnt, 0, 512 * 4, stream);
    hipMemsetAsync(bnacc, 0, 2 * F1 * 8, stream);

    const int eb = (E + CHUNK - 1) / CHUNK;

    hist_k<<<eb, 256, 0, stream>>>(dst, bucketcnt, E, NBUCK);
    bscan_k<<<1, 512, 0, stream>>>(bucketcnt, bucketbase, bucketcur, NBUCK, E);
    binpass_k<<<eb, 256, 0, stream>>>(src, dst, bucketcur, pairs, E);
    bdeg_k<<<NBUCK, 256, 0, stream>>>(pairs, bucketbase, degi, pbucketcnt, N);
    pscan_k<<<1, 512, 0, stream>>>(pbucketcnt, pbase, rowptr, NBUCK, N);
    bucket2_k<<<NBUCK, 256, 0, stream>>>(pairs, bucketbase, degi, pbase, dinv, rowptr, srcsorted, N);

    gemm1_k<<<(N + 63) / 64, 256, 0, stream>>>(x, W1, dinv, h, N);
    hipMemsetAsync(h + (size_t)N * 64, 0, 64 * 4, stream);   // zero dummy row N

    agg1_k<<<N, 64, 0, stream>>>(h, dinv, rowptr, srcsorted, b1, z, N);
    bnstats_k<<<512, 64, 0, stream>>>(z, bnacc, N);
    bnfinal_k<<<1, F1, 0, stream>>>(bnacc, gamma, beta, scale, shift, N);

    gemm2_k<<<(N + 63) / 64, 256, 0, stream>>>(z, W2, scale, shift, prelu_a, dinv, h2, N);
    hipMemsetAsync(h2 + (size_t)N * 32, 0, 32 * 4, stream);  // zero dummy row N (h2 layout)

    agg2_k<<<(N + 1) / 2, 64, 0, stream>>>(h2, dinv, rowptr, srcsorted, b2, (float2*)out, N);
}